// Round 6
// baseline (247.370 us; speedup 1.0000x reference)
//
#include <hip/hip_runtime.h>
#include <cmath>

#define N_NODES 1500
#define NBLK    1024
#define NTHR    256

// bf16 helpers (bf16 <-> f32 are pure bit ops)
__device__ __forceinline__ float blo(unsigned u) {
    union { unsigned i; float f; } v; v.i = u << 16; return v.f;
}
__device__ __forceinline__ float bhi(unsigned u) {
    union { unsigned i; float f; } v; v.i = u & 0xffff0000u; return v.f;
}
__device__ __forceinline__ ushort f2bf(float f) {
    union { float f; unsigned u; } v; v.f = f;
    return (ushort)((v.u + 0x7fffu + ((v.u >> 16) & 1u)) >> 16);  // RNE
}

// Fused kernel, ONE launch.
// Phase 1: htab[i][k] = bf16(h1[i,k]+b1[k]), htab[i][64+k] = bf16(h2[i,k]).
//   Block b covers rows {b, b+1024}: 2 row-slots x 128 threads (64 cols x 2 halves).
// Prefetch: edge indices + noise (independent of htab) issued BEFORE the barrier
//   so their HBM latency hides under the barrier wait.
// Barrier: one atomic arrive per block; POLL WITH RELAXED DEVICE-SCOPE LOADS
//   (R5 post-mortem: RMW-polling serialized at the coherence point -> ~90us).
//   Co-residency: __launch_bounds__(256,4) -> 4 blocks/CU x 256 CU = 1024 = grid.
// Phase 2: 8 edges per wave, 2 jobs per wave (R3-verified math).
__global__ __launch_bounds__(NTHR, 4)
void pg_fused(const float* __restrict__ embed,
              const float* __restrict__ W1,
              const float* __restrict__ b1,
              const int* __restrict__ e0,
              const int* __restrict__ e1,
              const float* __restrict__ noise,
              const float* __restrict__ tmp_p,
              const float* __restrict__ W2,
              const float* __restrict__ b2,
              unsigned* __restrict__ ctr,
              ushort* __restrict__ htab,
              float* __restrict__ out,
              int E) {
    const int t = threadIdx.x;
    const int b = blockIdx.x;

    // ---------------- Phase 1: h tables ----------------
    {
        const int slot = t >> 7;          // 0/1: row b / row b+1024
        const int tt   = t & 127;
        const int k    = tt & 63;
        const int half = tt >> 6;
        const int r    = b + slot * NBLK;

        __shared__ float emb_s[2][64];
        if (r < N_NODES && tt < 64) emb_s[slot][tt] = embed[r * 64 + tt];
        __syncthreads();

        if (r < N_NODES) {
            const float* wcol = W1 + (half << 6) * 64 + k;   // column k of W1 half
            float a0 = (half == 0) ? b1[k] : 0.0f;
            float a1 = 0.0f, a2 = 0.0f, a3 = 0.0f;
#pragma unroll
            for (int f = 0; f < 64; f += 4) {
                a0 = fmaf(emb_s[slot][f + 0], wcol[(f + 0) * 64], a0);
                a1 = fmaf(emb_s[slot][f + 1], wcol[(f + 1) * 64], a1);
                a2 = fmaf(emb_s[slot][f + 2], wcol[(f + 2) * 64], a2);
                a3 = fmaf(emb_s[slot][f + 3], wcol[(f + 3) * 64], a3);
            }
            htab[r * 128 + half * 64 + k] = f2bf((a0 + a1) + (a2 + a3));
        }
    }

    // ---------------- Pre-barrier prefetch (htab-independent) ----------------
    const int wave = (b << 2) + (t >> 6);   // 0..4095
    const int lane = t & 63;
    const int g    = lane >> 3;             // edge slot within wave
    const int l    = lane & 7;              // bf16x8 chunk within node row

    const int ej0 = wave * 8 + g;           // job 0 edge
    const int ej1 = (wave + 4096) * 8 + g;  // job 1 edge
    const bool v0 = (ej0 < E), v1 = (ej1 < E);
    const int i0 = v0 ? ej0 : 0, i1 = v1 ? ej1 : 0;

    const int r0 = e0[i0], c0 = e1[i0];
    const int r1 = e0[i1], c1 = e1[i1];

    float nv0 = 0.5f, nv1 = 0.5f;
    if (l < 2) {
        nv0 = noise[(l == 0) ? (r0 * N_NODES + c0) : (c0 * N_NODES + r0)];
        nv1 = noise[(l == 0) ? (r1 * N_NODES + c1) : (c1 * N_NODES + r1)];
    }
    const float bb    = b2[0];
    const float inv_t = 1.0f / tmp_p[0];
    const float4 w2a = ((const float4*)W2)[l * 2];
    const float4 w2b = ((const float4*)W2)[l * 2 + 1];

    // ---------------- Grid barrier (load-polling) ----------------
    __threadfence();                 // release htab stores device-wide
    __syncthreads();
    if (t == 0) {
        __hip_atomic_fetch_add(ctr, 1u, __ATOMIC_RELEASE, __HIP_MEMORY_SCOPE_AGENT);
        while (__hip_atomic_load(ctr, __ATOMIC_ACQUIRE, __HIP_MEMORY_SCOPE_AGENT)
               < (unsigned)NBLK) {
            __builtin_amdgcn_s_sleep(4);
        }
    }
    __syncthreads();
    __threadfence();                 // acquire side for all threads

    // ---------------- Phase 2: edges (2 jobs) ----------------
#pragma unroll
    for (int j = 0; j < 2; ++j) {
        const int  e     = j ? ej1 : ej0;
        const bool valid = j ? v1  : v0;
        const int  r     = j ? r1  : r0;
        const int  c     = j ? c1  : c0;
        const float nv   = j ? nv1 : nv0;

        const uint4* hr = (const uint4*)(htab + r * 128);
        const uint4* hc = (const uint4*)(htab + c * 128);
        const uint4 h1r = hr[l];
        const uint4 h2r = hr[l + 8];
        const uint4 h1c = hc[l];
        const uint4 h2c = hc[l + 8];

        float p = fmaxf(blo(h1r.x) + blo(h2c.x), 0.0f) * w2a.x;
        p = fmaf(fmaxf(bhi(h1r.x) + bhi(h2c.x), 0.0f), w2a.y, p);
        p = fmaf(fmaxf(blo(h1r.y) + blo(h2c.y), 0.0f), w2a.z, p);
        p = fmaf(fmaxf(bhi(h1r.y) + bhi(h2c.y), 0.0f), w2a.w, p);
        p = fmaf(fmaxf(blo(h1r.z) + blo(h2c.z), 0.0f), w2b.x, p);
        p = fmaf(fmaxf(bhi(h1r.z) + bhi(h2c.z), 0.0f), w2b.y, p);
        p = fmaf(fmaxf(blo(h1r.w) + blo(h2c.w), 0.0f), w2b.z, p);
        p = fmaf(fmaxf(bhi(h1r.w) + bhi(h2c.w), 0.0f), w2b.w, p);

        float s = fmaxf(blo(h1c.x) + blo(h2r.x), 0.0f) * w2a.x;
        s = fmaf(fmaxf(bhi(h1c.x) + bhi(h2r.x), 0.0f), w2a.y, s);
        s = fmaf(fmaxf(blo(h1c.y) + blo(h2r.y), 0.0f), w2a.z, s);
        s = fmaf(fmaxf(bhi(h1c.y) + bhi(h2r.y), 0.0f), w2a.w, s);
        s = fmaf(fmaxf(blo(h1c.z) + blo(h2r.z), 0.0f), w2b.x, s);
        s = fmaf(fmaxf(bhi(h1c.z) + bhi(h2r.z), 0.0f), w2b.y, s);
        s = fmaf(fmaxf(blo(h1c.w) + blo(h2r.w), 0.0f), w2b.z, s);
        s = fmaf(fmaxf(bhi(h1c.w) + bhi(h2r.w), 0.0f), w2b.w, s);

        // combined reduction: parity swap folds p/s in one shuffle, then xor 2,4
        const bool odd = (l & 1);
        float w = odd ? s : p;
        float z = odd ? p : s;
        w += __shfl_xor(z, 1, 64);
        w += __shfl_xor(w, 2, 64);
        w += __shfl_xor(w, 4, 64);
        // l==0: fwd sum, l==1: rev sum

        float gate = 0.0f;
        if (l < 2) {
            const float x = (__logf(nv / (1.0f - nv)) + w + bb) * inv_t;
            gate = 1.0f / (1.0f + __expf(-x));
        }
        const float gother = __shfl_xor(gate, 1, 64);
        if (valid && l == 0) out[e] = 0.5f * (gate + gother);
    }
}

extern "C" void kernel_launch(void* const* d_in, const int* in_sizes, int n_in,
                              void* d_out, int out_size, void* d_ws, size_t ws_size,
                              hipStream_t stream) {
    const float* embed = (const float*)d_in[0];
    const int*   eidx  = (const int*)d_in[1];
    const float* noise = (const float*)d_in[2];
    const float* tmp_p = (const float*)d_in[3];
    const float* W1    = (const float*)d_in[4];
    const float* b1    = (const float*)d_in[5];
    const float* W2    = (const float*)d_in[6];
    const float* b2    = (const float*)d_in[7];
    float* out = (float*)d_out;

    const int E = in_sizes[1] / 2;           // edge_index is [2, E]
    const int* e0 = eidx;
    const int* e1 = eidx + E;

    // ws layout: [0,4) barrier counter (zeroed every call); [128,.) htab bf16
    unsigned* ctr  = (unsigned*)d_ws;
    ushort*   htab = (ushort*)((char*)d_ws + 128);

    hipMemsetAsync(ctr, 0, 4, stream);

    pg_fused<<<NBLK, NTHR, 0, stream>>>(embed, W1, b1, e0, e1, noise,
                                        tmp_p, W2, b2, ctr, htab, out, E);
}

// Round 7
// 14.199 us; speedup vs baseline: 17.4219x; 17.4219x over previous
//
#include <hip/hip_runtime.h>
#include <cmath>

#define N_NODES 1500

// bf16 helpers (bf16 <-> f32 are pure bit ops)
__device__ __forceinline__ float blo(unsigned u) {
    union { unsigned i; float f; } v; v.i = u << 16; return v.f;
}
__device__ __forceinline__ float bhi(unsigned u) {
    union { unsigned i; float f; } v; v.i = u & 0xffff0000u; return v.f;
}
__device__ __forceinline__ ushort f2bf(float f) {
    union { float f; unsigned u; } v; v.f = f;
    return (ushort)((v.u + 0x7fffu + ((v.u >> 16) & 1u)) >> 16);  // RNE
}

// Kernel 1: htab[i][k] = bf16(h1[i,k]+b1[k]), htab[i][64+k] = bf16(h2[i,k]).
// 750 blocks x 256 threads; block b does rows {2b, 2b+1} (slot = t>>7),
// within a row-slot 128 threads = 64 cols x 2 W1-halves.
__global__ __launch_bounds__(256)
void pg_compute_h(const float* __restrict__ embed,
                  const float* __restrict__ W1,
                  const float* __restrict__ b1,
                  ushort* __restrict__ htab) {
    const int t    = threadIdx.x;
    const int slot = t >> 7;
    const int tt   = t & 127;
    const int k    = tt & 63;
    const int half = tt >> 6;
    const int r    = blockIdx.x * 2 + slot;      // < 1500 always

    __shared__ float emb_s[2][64];
    if (tt < 64) emb_s[slot][tt] = embed[r * 64 + tt];
    __syncthreads();

    const float* wcol = W1 + (half << 6) * 64 + k;   // column k of W1 half
    float a0 = (half == 0) ? b1[k] : 0.0f;
    float a1 = 0.0f, a2 = 0.0f, a3 = 0.0f;
#pragma unroll
    for (int f = 0; f < 64; f += 4) {
        a0 = fmaf(emb_s[slot][f + 0], wcol[(f + 0) * 64], a0);
        a1 = fmaf(emb_s[slot][f + 1], wcol[(f + 1) * 64], a1);
        a2 = fmaf(emb_s[slot][f + 2], wcol[(f + 2) * 64], a2);
        a3 = fmaf(emb_s[slot][f + 3], wcol[(f + 3) * 64], a3);
    }
    htab[r * 128 + half * 64 + k] = f2bf((a0 + a1) + (a2 + a3));
}

// Kernel 2: 8 edges per wave, 2 independent jobs per wave (ILP).
// Group g = lane>>3 owns one edge; lane l = lane&7 holds dims 8l..8l+7.
// Indices + noise for BOTH jobs prefetched up front (R5-verified body).
__global__ __launch_bounds__(256)
void pg_edge(const int* __restrict__ e0,
             const int* __restrict__ e1,
             const float* __restrict__ noise,
             const float* __restrict__ tmp_p,
             const float* __restrict__ W2,
             const float* __restrict__ b2,
             const ushort* __restrict__ htab,
             float* __restrict__ out,
             int E) {
    const int t    = threadIdx.x;
    const int wave = blockIdx.x * 4 + (t >> 6);   // 0..4095
    const int lane = t & 63;
    const int g    = lane >> 3;                   // edge slot within wave
    const int l    = lane & 7;                    // bf16x8 chunk within node row

    const int ej0 = wave * 8 + g;                 // job 0 edge
    const int ej1 = (wave + 4096) * 8 + g;        // job 1 edge
    const bool v0 = (ej0 < E), v1 = (ej1 < E);
    const int i0 = v0 ? ej0 : 0, i1 = v1 ? ej1 : 0;

    const int r0 = e0[i0], c0 = e1[i0];
    const int r1 = e0[i1], c1 = e1[i1];

    float nv0 = 0.5f, nv1 = 0.5f;
    if (l < 2) {
        nv0 = noise[(l == 0) ? (r0 * N_NODES + c0) : (c0 * N_NODES + r0)];
        nv1 = noise[(l == 0) ? (r1 * N_NODES + c1) : (c1 * N_NODES + r1)];
    }
    const float bb    = b2[0];
    const float inv_t = 1.0f / tmp_p[0];
    const float4 w2a = ((const float4*)W2)[l * 2];
    const float4 w2b = ((const float4*)W2)[l * 2 + 1];

#pragma unroll
    for (int j = 0; j < 2; ++j) {
        const int  e     = j ? ej1 : ej0;
        const bool valid = j ? v1  : v0;
        const int  r     = j ? r1  : r0;
        const int  c     = j ? c1  : c0;
        const float nv   = j ? nv1 : nv0;

        const uint4* hr = (const uint4*)(htab + r * 128);
        const uint4* hc = (const uint4*)(htab + c * 128);
        const uint4 h1r = hr[l];
        const uint4 h2r = hr[l + 8];
        const uint4 h1c = hc[l];
        const uint4 h2c = hc[l + 8];

        float p = fmaxf(blo(h1r.x) + blo(h2c.x), 0.0f) * w2a.x;
        p = fmaf(fmaxf(bhi(h1r.x) + bhi(h2c.x), 0.0f), w2a.y, p);
        p = fmaf(fmaxf(blo(h1r.y) + blo(h2c.y), 0.0f), w2a.z, p);
        p = fmaf(fmaxf(bhi(h1r.y) + bhi(h2c.y), 0.0f), w2a.w, p);
        p = fmaf(fmaxf(blo(h1r.z) + blo(h2c.z), 0.0f), w2b.x, p);
        p = fmaf(fmaxf(bhi(h1r.z) + bhi(h2c.z), 0.0f), w2b.y, p);
        p = fmaf(fmaxf(blo(h1r.w) + blo(h2c.w), 0.0f), w2b.z, p);
        p = fmaf(fmaxf(bhi(h1r.w) + bhi(h2c.w), 0.0f), w2b.w, p);

        float s = fmaxf(blo(h1c.x) + blo(h2r.x), 0.0f) * w2a.x;
        s = fmaf(fmaxf(bhi(h1c.x) + bhi(h2r.x), 0.0f), w2a.y, s);
        s = fmaf(fmaxf(blo(h1c.y) + blo(h2r.y), 0.0f), w2a.z, s);
        s = fmaf(fmaxf(bhi(h1c.y) + bhi(h2r.y), 0.0f), w2a.w, s);
        s = fmaf(fmaxf(blo(h1c.z) + blo(h2r.z), 0.0f), w2b.x, s);
        s = fmaf(fmaxf(bhi(h1c.z) + bhi(h2r.z), 0.0f), w2b.y, s);
        s = fmaf(fmaxf(blo(h1c.w) + blo(h2r.w), 0.0f), w2b.z, s);
        s = fmaf(fmaxf(bhi(h1c.w) + bhi(h2r.w), 0.0f), w2b.w, s);

        // combined reduction: parity swap folds p/s in one shuffle, then xor 2,4
        const bool odd = (l & 1);
        float w = odd ? s : p;
        float z = odd ? p : s;
        w += __shfl_xor(z, 1, 64);
        w += __shfl_xor(w, 2, 64);
        w += __shfl_xor(w, 4, 64);
        // l==0: fwd sum, l==1: rev sum

        float gate = 0.0f;
        if (l < 2) {
            const float x = (__logf(nv / (1.0f - nv)) + w + bb) * inv_t;
            gate = 1.0f / (1.0f + __expf(-x));
        }
        const float gother = __shfl_xor(gate, 1, 64);
        if (valid && l == 0) out[e] = 0.5f * (gate + gother);
    }
}

extern "C" void kernel_launch(void* const* d_in, const int* in_sizes, int n_in,
                              void* d_out, int out_size, void* d_ws, size_t ws_size,
                              hipStream_t stream) {
    const float* embed = (const float*)d_in[0];
    const int*   eidx  = (const int*)d_in[1];
    const float* noise = (const float*)d_in[2];
    const float* tmp_p = (const float*)d_in[3];
    const float* W1    = (const float*)d_in[4];
    const float* b1    = (const float*)d_in[5];
    const float* W2    = (const float*)d_in[6];
    const float* b2    = (const float*)d_in[7];
    float* out = (float*)d_out;

    const int E = in_sizes[1] / 2;           // edge_index is [2, E]
    const int* e0 = eidx;
    const int* e1 = eidx + E;

    ushort* htab = (ushort*)d_ws;            // [N_NODES][128] bf16

    pg_compute_h<<<N_NODES / 2, 256, 0, stream>>>(embed, W1, b1, htab);

    const int nwaves = (E + 15) / 16;        // 2 jobs x 8 edges per wave
    const int grid   = (nwaves + 3) / 4;     // 4 waves per block
    pg_edge<<<grid, 256, 0, stream>>>(e0, e1, noise, tmp_p, W2, b2,
                                      htab, out, E);
}